// Round 1
// baseline (2000.101 us; speedup 1.0000x reference)
//
#include <hip/hip_runtime.h>

#define DD 256

// ---------------- CSR build ----------------

__global__ void zero_i32_kernel(int* p, int n) {
  int i = blockIdx.x * 256 + threadIdx.x;
  if (i < n) p[i] = 0;
}

__global__ void zero_f32_kernel(float* p, int n) {
  int i = blockIdx.x * 256 + threadIdx.x;
  if (i < n) p[i] = 0.f;
}

__global__ void count_kernel(const int* __restrict__ dst, int* __restrict__ cnt, int e) {
  int i = blockIdx.x * 256 + threadIdx.x;
  if (i < e) atomicAdd(&cnt[dst[i]], 1);
}

__global__ void scan_block_kernel(const int* __restrict__ cnt, int* __restrict__ out,
                                  int* __restrict__ bsum, int n) {
  __shared__ int sh[256];
  int tid = threadIdx.x;
  int base = blockIdx.x * 1024 + tid * 4;
  int v0 = (base + 0 < n) ? cnt[base + 0] : 0;
  int v1 = (base + 1 < n) ? cnt[base + 1] : 0;
  int v2 = (base + 2 < n) ? cnt[base + 2] : 0;
  int v3 = (base + 3 < n) ? cnt[base + 3] : 0;
  int s = v0 + v1 + v2 + v3;
  sh[tid] = s;
  __syncthreads();
  for (int d = 1; d < 256; d <<= 1) {
    int t = (tid >= d) ? sh[tid - d] : 0;
    __syncthreads();
    sh[tid] += t;
    __syncthreads();
  }
  int excl = sh[tid] - s;
  if (base + 0 < n) out[base + 0] = excl;
  excl += v0;
  if (base + 1 < n) out[base + 1] = excl;
  excl += v1;
  if (base + 2 < n) out[base + 2] = excl;
  excl += v2;
  if (base + 3 < n) out[base + 3] = excl;
  if (tid == 255) bsum[blockIdx.x] = sh[255];
}

__global__ void scan_partials_kernel(int* bsum, int nb) {
  if (threadIdx.x == 0 && blockIdx.x == 0) {
    int acc = 0;
    for (int i = 0; i < nb; ++i) { int t = bsum[i]; bsum[i] = acc; acc += t; }
  }
}

__global__ void finalize_kernel(int* __restrict__ off, const int* __restrict__ bsum,
                                int* __restrict__ cursor, const int* __restrict__ cnt,
                                float* __restrict__ dis, int n, int e) {
  int i = blockIdx.x * 256 + threadIdx.x;
  if (i < n) {
    int o = off[i] + bsum[i >> 10];
    off[i] = o;
    cursor[i] = o;
    dis[i] = rsqrtf((float)(cnt[i] + 1));  // deg includes self-loop
  }
  if (i == 0 && blockIdx.x == 0) off[n] = e;
}

__global__ void fill_kernel(const int* __restrict__ src, const int* __restrict__ dst,
                            int* __restrict__ cursor, int* __restrict__ csr_src, int e) {
  int i = blockIdx.x * 256 + threadIdx.x;
  if (i < e) {
    int d = dst[i];
    int p = atomicAdd(&cursor[d], 1);
    csr_src[p] = src[i];
  }
}

// ---------------- GEMM: C[n][256] = act(affine(A)[n][K] @ W[K][256] + bias) ----------------
// BM=64, BN=128, BK=16; 256 threads, 4x8 per thread.

template <int K, bool AFFINE, bool RELU>
__global__ __launch_bounds__(256) void gemm_kernel(
    const float* __restrict__ A, const float* __restrict__ W,
    const float* __restrict__ bias, const float* __restrict__ scale,
    const float* __restrict__ shift, float* __restrict__ C, int nrows) {
  __shared__ float As[16][68];   // [k][row], +4 pad keeps float4 alignment
  __shared__ float Ws[16][128];  // [k][col]
  const int tid = threadIdx.x;
  const int row0 = blockIdx.x * 64;
  const int col0 = blockIdx.y * 128;
  const int tm = (tid >> 4) << 2;   // 0..60
  const int tn = (tid & 15) << 3;   // 0..120
  const int a_r = tid >> 2;         // 0..63
  const int a_c = (tid & 3) << 2;   // 0,4,8,12
  const int w_r = tid >> 4;         // 0..15
  const int w_c = (tid & 15) << 3;  // 0..120

  float acc[4][8];
#pragma unroll
  for (int i = 0; i < 4; ++i)
#pragma unroll
    for (int j = 0; j < 8; ++j) acc[i][j] = 0.f;

  for (int k0 = 0; k0 < K; k0 += 16) {
    float4 av;
    int gr = row0 + a_r;
    if (gr < nrows)
      av = *(const float4*)(A + (size_t)gr * K + (k0 + a_c));
    else
      av = make_float4(0.f, 0.f, 0.f, 0.f);
    if (AFFINE) {
      av.x = av.x * scale[k0 + a_c + 0] + shift[k0 + a_c + 0];
      av.y = av.y * scale[k0 + a_c + 1] + shift[k0 + a_c + 1];
      av.z = av.z * scale[k0 + a_c + 2] + shift[k0 + a_c + 2];
      av.w = av.w * scale[k0 + a_c + 3] + shift[k0 + a_c + 3];
    }
    const float* wp = W + (size_t)(k0 + w_r) * 256 + col0 + w_c;
    float4 wv0 = *(const float4*)(wp);
    float4 wv1 = *(const float4*)(wp + 4);
    As[a_c + 0][a_r] = av.x;
    As[a_c + 1][a_r] = av.y;
    As[a_c + 2][a_r] = av.z;
    As[a_c + 3][a_r] = av.w;
    *(float4*)&Ws[w_r][w_c] = wv0;
    *(float4*)&Ws[w_r][w_c + 4] = wv1;
    __syncthreads();
#pragma unroll
    for (int kk = 0; kk < 16; ++kk) {
      float4 a = *(const float4*)&As[kk][tm];
      float4 b0 = *(const float4*)&Ws[kk][tn];
      float4 b1 = *(const float4*)&Ws[kk][tn + 4];
      float ar[4] = {a.x, a.y, a.z, a.w};
      float br[8] = {b0.x, b0.y, b0.z, b0.w, b1.x, b1.y, b1.z, b1.w};
#pragma unroll
      for (int i = 0; i < 4; ++i)
#pragma unroll
        for (int j = 0; j < 8; ++j) acc[i][j] = fmaf(ar[i], br[j], acc[i][j]);
    }
    __syncthreads();
  }

  float bj[8];
#pragma unroll
  for (int j = 0; j < 8; ++j) bj[j] = bias ? bias[col0 + tn + j] : 0.f;
#pragma unroll
  for (int i = 0; i < 4; ++i) {
    int gr = row0 + tm + i;
    if (gr >= nrows) continue;
    float o[8];
#pragma unroll
    for (int j = 0; j < 8; ++j) {
      float v = acc[i][j] + bj[j];
      if (RELU) v = fmaxf(v, 0.f);
      o[j] = v;
    }
    float* cp = C + (size_t)gr * 256 + col0 + tn;
    *(float4*)cp = make_float4(o[0], o[1], o[2], o[3]);
    *(float4*)(cp + 4) = make_float4(o[4], o[5], o[6], o[7]);
  }
}

// ---------------- GCN gather: out[i] = relu(sum_e norm*m[src] + dis_i^2*m[i] + b) ----------------
// one wave per node, float4 per lane (64*4 = 256 features)

__global__ __launch_bounds__(256) void gather_kernel(
    const float* __restrict__ m, const int* __restrict__ off,
    const int* __restrict__ csr_src, const float* __restrict__ dis,
    const float* __restrict__ bias, float* __restrict__ out, int n) {
  int node = blockIdx.x * 4 + (threadIdx.x >> 6);
  if (node >= n) return;
  int lane = threadIdx.x & 63;
  float di = dis[node];
  float4 v = *(const float4*)(m + (size_t)node * DD + lane * 4);
  float w = di * di;
  float ax = w * v.x, ay = w * v.y, az = w * v.z, aw = w * v.w;
  int e0 = off[node], e1 = off[node + 1];
  int e = e0;
  for (; e + 1 < e1; e += 2) {
    int s0 = csr_src[e], s1 = csr_src[e + 1];
    float w0 = dis[s0] * di, w1 = dis[s1] * di;
    float4 u0 = *(const float4*)(m + (size_t)s0 * DD + lane * 4);
    float4 u1 = *(const float4*)(m + (size_t)s1 * DD + lane * 4);
    ax = fmaf(w0, u0.x, ax); ay = fmaf(w0, u0.y, ay);
    az = fmaf(w0, u0.z, az); aw = fmaf(w0, u0.w, aw);
    ax = fmaf(w1, u1.x, ax); ay = fmaf(w1, u1.y, ay);
    az = fmaf(w1, u1.z, az); aw = fmaf(w1, u1.w, aw);
  }
  if (e < e1) {
    int s0 = csr_src[e];
    float w0 = dis[s0] * di;
    float4 u0 = *(const float4*)(m + (size_t)s0 * DD + lane * 4);
    ax = fmaf(w0, u0.x, ax); ay = fmaf(w0, u0.y, ay);
    az = fmaf(w0, u0.z, az); aw = fmaf(w0, u0.w, aw);
  }
  float4 bb = *(const float4*)(bias + lane * 4);
  ax = fmaxf(ax + bb.x, 0.f);
  ay = fmaxf(ay + bb.y, 0.f);
  az = fmaxf(az + bb.z, 0.f);
  aw = fmaxf(aw + bb.w, 0.f);
  *(float4*)(out + (size_t)node * DD + lane * 4) = make_float4(ax, ay, az, aw);
}

// ---------------- BatchNorm stats (biased var) ----------------

__global__ void bn_partial_kernel(const float* __restrict__ h, float* __restrict__ sums, int n) {
  int c = threadIdx.x;  // 256
  float s = 0.f, q = 0.f;
  for (int r = blockIdx.x; r < n; r += gridDim.x) {
    float v = h[(size_t)r * DD + c];
    s += v;
    q += v * v;
  }
  atomicAdd(&sums[c], s);
  atomicAdd(&sums[DD + c], q);
}

__global__ void bn_finalize_kernel(const float* __restrict__ sums, const float* __restrict__ g,
                                   const float* __restrict__ b, float* __restrict__ scale,
                                   float* __restrict__ shift, float inv_n) {
  int c = threadIdx.x;  // 256
  float mu = sums[c] * inv_n;
  float var = sums[DD + c] * inv_n - mu * mu;
  float inv = rsqrtf(var + 1e-5f);
  float sc = g[c] * inv;
  scale[c] = sc;
  shift[c] = b[c] - mu * sc;
}

// ---------------- global mean pool (batch_index is sorted) ----------------

__global__ void pool_kernel(const float* __restrict__ h, const int* __restrict__ batch,
                            float* __restrict__ pooled, int n) {
  int g = blockIdx.x;
  int c = threadIdx.x;
  int lo = 0, hi = n;
  while (lo < hi) { int mid = (lo + hi) >> 1; if (batch[mid] < g) lo = mid + 1; else hi = mid; }
  int start = lo;
  hi = n;
  while (lo < hi) { int mid = (lo + hi) >> 1; if (batch[mid] <= g) lo = mid + 1; else hi = mid; }
  int end = lo;
  float a0 = 0.f, a1 = 0.f, a2 = 0.f, a3 = 0.f;
  int r = start;
  for (; r + 3 < end; r += 4) {
    a0 += h[(size_t)(r + 0) * DD + c];
    a1 += h[(size_t)(r + 1) * DD + c];
    a2 += h[(size_t)(r + 2) * DD + c];
    a3 += h[(size_t)(r + 3) * DD + c];
  }
  for (; r < end; ++r) a0 += h[(size_t)r * DD + c];
  float s = (a0 + a1) + (a2 + a3);
  int cg = end - start;
  pooled[g * DD + c] = s / (float)(cg > 1 ? cg : 1);
}

// ---------------- MLP head ----------------
// z = [pooled, pooled]; l1: 512->512 relu

__global__ void mlp1_kernel(const float* __restrict__ pooled, const float* __restrict__ W,
                            const float* __restrict__ b, float* __restrict__ out) {
  __shared__ float p[256];
  int g = blockIdx.x;
  int j = blockIdx.y * 256 + threadIdx.x;
  p[threadIdx.x] = pooled[g * 256 + threadIdx.x];
  __syncthreads();
  float acc = b[j];
#pragma unroll 8
  for (int k = 0; k < 512; ++k) acc = fmaf(p[k & 255], W[k * 512 + j], acc);
  out[g * 512 + j] = fmaxf(acc, 0.f);
}

__global__ void mlp2_kernel(const float* __restrict__ z1, const float* __restrict__ W,
                            const float* __restrict__ b, float* __restrict__ out) {
  __shared__ float p[512];
  int g = blockIdx.x;
  p[threadIdx.x] = z1[g * 512 + threadIdx.x];
  p[256 + threadIdx.x] = z1[g * 512 + 256 + threadIdx.x];
  __syncthreads();
  float acc = b[threadIdx.x];
#pragma unroll 8
  for (int k = 0; k < 512; ++k) acc = fmaf(p[k], W[k * 256 + threadIdx.x], acc);
  out[g * 256 + threadIdx.x] = fmaxf(acc, 0.f);
}

__global__ void mlp3_kernel(const float* __restrict__ z2, const float* __restrict__ W,
                            const float* __restrict__ b, float* __restrict__ out) {
  int g = blockIdx.x;
  int lane = threadIdx.x;  // 64
  float acc[10];
#pragma unroll
  for (int o = 0; o < 10; ++o) acc[o] = 0.f;
  for (int k = lane; k < 256; k += 64) {
    float v = z2[g * 256 + k];
#pragma unroll
    for (int o = 0; o < 10; ++o) acc[o] = fmaf(v, W[k * 10 + o], acc[o]);
  }
#pragma unroll
  for (int o = 0; o < 10; ++o) {
    float s = acc[o];
    for (int d = 32; d > 0; d >>= 1) s += __shfl_down(s, d);
    if (lane == 0) out[g * 10 + o] = s + b[o];
  }
}

// ---------------- launch ----------------

extern "C" void kernel_launch(void* const* d_in, const int* in_sizes, int n_in,
                              void* d_out, int out_size, void* d_ws, size_t ws_size,
                              hipStream_t stream) {
  const float* x = (const float*)d_in[0];
  const int* ei = (const int*)d_in[1];
  const int* batch = (const int*)d_in[2];
  const float* fl_W = (const float*)d_in[3];
  const float* fl_b = (const float*)d_in[4];
  const float* conv1_W = (const float*)d_in[5];
  const float* conv1_b = (const float*)d_in[6];
  const float* tr1_W = (const float*)d_in[7];
  const float* tr1_b = (const float*)d_in[8];
  const float* bn1_g = (const float*)d_in[9];
  const float* bn1_b = (const float*)d_in[10];
  const float* convs_W = (const float*)d_in[11];
  const float* convs_b = (const float*)d_in[12];
  const float* trs_W = (const float*)d_in[13];
  const float* trs_b = (const float*)d_in[14];
  const float* bns_g = (const float*)d_in[15];
  const float* bns_b = (const float*)d_in[16];
  const float* l1_W = (const float*)d_in[17];
  const float* l1_b = (const float*)d_in[18];
  const float* l2_W = (const float*)d_in[19];
  const float* l2_b = (const float*)d_in[20];
  const float* l3_W = (const float*)d_in[21];
  const float* l3_b = (const float*)d_in[22];

  const int N = in_sizes[0] / 128;
  const int E = in_sizes[1] / 2;
  const int G = out_size / 10;
  const int NL = in_sizes[11] / (256 * 256);
  const int* src = ei;
  const int* dst = ei + E;

  char* ws = (char*)d_ws;
  size_t o = 0;
  auto alloc = [&](size_t bytes) -> char* {
    o = (o + 255) & ~(size_t)255;
    char* p = ws + o;
    o += bytes;
    return p;
  };
  float* hA = (float*)alloc((size_t)N * DD * 4);
  float* hB = (float*)alloc((size_t)N * DD * 4);
  float* dis = (float*)alloc((size_t)N * 4);
  int* cnt = (int*)alloc((size_t)N * 4);
  int* off = (int*)alloc((size_t)(N + 1) * 4);
  int* cursor = (int*)alloc((size_t)N * 4);
  int* bsum = (int*)alloc(64 * 4);
  int* csr = (int*)alloc((size_t)E * 4);
  float* bnsums = (float*)alloc(512 * 4);
  float* scalev = (float*)alloc(256 * 4);
  float* shiftv = (float*)alloc(256 * 4);
  float* pooled = (float*)alloc((size_t)G * 256 * 4);
  float* z1 = (float*)alloc((size_t)G * 512 * 4);
  float* z2 = (float*)alloc((size_t)G * 256 * 4);

  dim3 b256(256);

  // CSR build (per call; deterministic work)
  zero_i32_kernel<<<(N + 255) / 256, b256, 0, stream>>>(cnt, N);
  count_kernel<<<(E + 255) / 256, b256, 0, stream>>>(dst, cnt, E);
  int nb = (N + 1023) / 1024;
  scan_block_kernel<<<nb, b256, 0, stream>>>(cnt, off, bsum, N);
  scan_partials_kernel<<<1, 64, 0, stream>>>(bsum, nb);
  finalize_kernel<<<(N + 255) / 256, b256, 0, stream>>>(off, bsum, cursor, cnt, dis, N, E);
  fill_kernel<<<(E + 255) / 256, b256, 0, stream>>>(src, dst, cursor, csr, E);

  dim3 ggrid((N + 63) / 64, 2);
  // h = x @ fl_W + fl_b
  gemm_kernel<128, false, false><<<ggrid, b256, 0, stream>>>(x, fl_W, fl_b, nullptr, nullptr, hA, N);

  float* cur = hA;
  float* alt = hB;
  for (int L = 0; L < 1 + NL; ++L) {
    const float* Wc = (L == 0) ? conv1_W : convs_W + (size_t)(L - 1) * 256 * 256;
    const float* bc = (L == 0) ? conv1_b : convs_b + (size_t)(L - 1) * 256;
    const float* gg = (L == 0) ? bn1_g : bns_g + (size_t)(L - 1) * 256;
    const float* gb = (L == 0) ? bn1_b : bns_b + (size_t)(L - 1) * 256;
    const float* Wt = (L == 0) ? tr1_W : trs_W + (size_t)(L - 1) * 256 * 256;
    const float* bt = (L == 0) ? tr1_b : trs_b + (size_t)(L - 1) * 256;

    // m = h @ Wc (no bias, no act)
    gemm_kernel<256, false, false><<<ggrid, b256, 0, stream>>>(cur, Wc, nullptr, nullptr, nullptr, alt, N);
    // h = relu(aggregate(m) + bc)
    gather_kernel<<<(N + 3) / 4, b256, 0, stream>>>(alt, off, csr, dis, bc, cur, N);
    // BN stats -> per-column scale/shift
    zero_f32_kernel<<<2, b256, 0, stream>>>(bnsums, 512);
    bn_partial_kernel<<<1024, b256, 0, stream>>>(cur, bnsums, N);
    bn_finalize_kernel<<<1, b256, 0, stream>>>(bnsums, gg, gb, scalev, shiftv, 1.0f / (float)N);
    // h = relu(bn(h) @ Wt + bt)  (BN affine fused into A-load)
    gemm_kernel<256, true, true><<<ggrid, b256, 0, stream>>>(cur, Wt, bt, scalev, shiftv, alt, N);
    float* t = cur; cur = alt; alt = t;
  }

  pool_kernel<<<G, b256, 0, stream>>>(cur, batch, pooled, N);
  dim3 m1grid(G, 2);
  mlp1_kernel<<<m1grid, b256, 0, stream>>>(pooled, l1_W, l1_b, z1);
  mlp2_kernel<<<G, b256, 0, stream>>>(z1, l2_W, l2_b, z2);
  mlp3_kernel<<<G, 64, 0, stream>>>(z2, l3_W, l3_b, (float*)d_out);
}